// Round 1
// baseline (3490.952 us; speedup 1.0000x reference)
//
#include <hip/hip_runtime.h>
#include <cstddef>

#define B_ 512
#define N_ 197
#define C_ 384
#define H_ 12
#define D_ 32
#define A_ 49
#define SCALE_ 0.17677669529663687f   // 32^-0.5
#define M_TOT (B_*N_)                 // 100864

// 16B store with only 4B alignment guarantee (rep rows have odd stride 197)
struct __attribute__((aligned(4))) F4U { float x, y, z, w; };

// ---------- bilinear 7x7 -> 14x14 (jax.image.resize half-pixel semantics) ----------
__device__ __forceinline__ float bilin7(const float* __restrict__ s, int i, int j) {
  float sy = 0.5f*(float)i - 0.25f;
  float sx = 0.5f*(float)j - 0.25f;
  float fy0 = floorf(sy), fx0 = floorf(sx);
  float fy = sy - fy0, fx = sx - fx0;
  int y0 = (int)fy0, x0 = (int)fx0;
  int y1 = y0 + 1, x1 = x0 + 1;
  y0 = min(max(y0, 0), 6); y1 = min(max(y1, 0), 6);
  x0 = min(max(x0, 0), 6); x1 = min(max(x1, 0), 6);
  float v00 = s[y0*7+x0], v01 = s[y0*7+x1], v10 = s[y1*7+x0], v11 = s[y1*7+x1];
  float t0 = v00 + (v01 - v00)*fx;
  float t1 = v10 + (v11 - v10)*fx;
  return t0 + (t1 - t0)*fy;
}

// pos_bias (H,A,197): [ac_bias | resize(an)+ah+aw]
__global__ void k_pos_bias(const float* __restrict__ an, const float* __restrict__ ah,
                           const float* __restrict__ aw, const float* __restrict__ ac,
                           float* __restrict__ pb) {
  int idx = blockIdx.x*256 + threadIdx.x;
  if (idx >= H_*A_*N_) return;
  int n = idx % N_;
  int ha = idx / N_;            // h*49 + a
  float v;
  if (n == 0) {
    v = ac[ha];
  } else {
    int t = n - 1, i = t/14, j = t%14;
    v = bilin7(an + (size_t)ha*49, i, j) + ah[ha*14 + i] + aw[ha*14 + j];
  }
  pb[idx] = v;
}

// agent_bias (H,197,A): row0 = ca_bias; rows 1..196 = resize(na)^T + ha + wa
__global__ void k_agent_bias(const float* __restrict__ na, const float* __restrict__ hab,
                             const float* __restrict__ wab, const float* __restrict__ ca,
                             float* __restrict__ ab) {
  int idx = blockIdx.x*256 + threadIdx.x;
  if (idx >= H_*N_*A_) return;
  int a = idx % A_;
  int n = (idx / A_) % N_;
  int h = idx / (A_*N_);
  float v;
  if (n == 0) {
    v = ca[h*A_ + a];
  } else {
    int t = n - 1, i = t/14, j = t%14;
    v = bilin7(na + (size_t)(h*A_ + a)*49, i, j) + hab[(h*14 + i)*A_ + a] + wab[(h*14 + j)*A_ + a];
  }
  ab[idx] = v;
}

// ---------- fp32 GEMM 128x128x16, 256 thr, 8x8/thread (two 4-wide fragments) ----------
__global__ __launch_bounds__(256) void k_gemm_qkv(
    const float* __restrict__ X, const float* __restrict__ W,
    float* __restrict__ Qo, float* __restrict__ Ko, float* __restrict__ Vo)
{
  __shared__ float As[16][132];
  __shared__ float Bs[16][132];
  const int tid = threadIdx.x;
  const int m0 = blockIdx.x * 128;
  const int j0 = blockIdx.y * 128;
  const int tm = (tid >> 4) & 15;
  const int tn = tid & 15;
  const int lk = (tid & 3) << 2;   // 0,4,8,12
  const int lr = tid >> 2;         // 0..63
  float acc[2][2][4][4];
  #pragma unroll
  for (int i2=0;i2<2;++i2)
    #pragma unroll
    for (int j2=0;j2<2;++j2)
      #pragma unroll
      for (int i=0;i<4;++i)
        #pragma unroll
        for (int j=0;j<4;++j) acc[i2][j2][i][j] = 0.f;

  const float* xp = X + (size_t)(m0 + lr)*C_ + lk;
  const float* wp = W + (size_t)(j0 + lr)*C_ + lk;

  for (int k0 = 0; k0 < C_; k0 += 16) {
    #pragma unroll
    for (int p = 0; p < 2; ++p) {
      float4 a4 = *reinterpret_cast<const float4*>(xp + k0 + (size_t)p*64*C_);
      float4 b4 = *reinterpret_cast<const float4*>(wp + k0 + (size_t)p*64*C_);
      int row = lr + p*64;
      As[lk+0][row]=a4.x; As[lk+1][row]=a4.y; As[lk+2][row]=a4.z; As[lk+3][row]=a4.w;
      Bs[lk+0][row]=b4.x; Bs[lk+1][row]=b4.y; Bs[lk+2][row]=b4.z; Bs[lk+3][row]=b4.w;
    }
    __syncthreads();
    #pragma unroll
    for (int kk = 0; kk < 16; ++kk) {
      float a[2][4], b[2][4];
      #pragma unroll
      for (int h2 = 0; h2 < 2; ++h2) {
        float4 av = *reinterpret_cast<const float4*>(&As[kk][h2*64 + tm*4]);
        a[h2][0]=av.x; a[h2][1]=av.y; a[h2][2]=av.z; a[h2][3]=av.w;
        float4 bv = *reinterpret_cast<const float4*>(&Bs[kk][h2*64 + tn*4]);
        b[h2][0]=bv.x; b[h2][1]=bv.y; b[h2][2]=bv.z; b[h2][3]=bv.w;
      }
      #pragma unroll
      for (int i2=0;i2<2;++i2)
        #pragma unroll
        for (int j2=0;j2<2;++j2)
          #pragma unroll
          for (int i=0;i<4;++i)
            #pragma unroll
            for (int j=0;j<4;++j)
              acc[i2][j2][i][j] += a[i2][i]*b[j2][j];
    }
    __syncthreads();
  }
  #pragma unroll
  for (int i2=0;i2<2;++i2) {
    #pragma unroll
    for (int i=0;i<4;++i) {
      int m = m0 + i2*64 + tm*4 + i;
      int bb = m / N_;
      int n  = m - bb*N_;
      #pragma unroll
      for (int j2=0;j2<2;++j2) {
        #pragma unroll
        for (int j=0;j<4;++j) {
          int col = j0 + j2*64 + tn*4 + j;
          int sec = col / C_;
          int c = col - sec*C_;
          float* dst = sec==0 ? Qo : (sec==1 ? Ko : Vo);
          dst[(((size_t)bb*H_ + (c>>5))*N_ + n)*D_ + (c&31)] = acc[i2][j2][i][j];
        }
      }
    }
  }
}

__global__ __launch_bounds__(256) void k_gemm_proj(
    const float* __restrict__ X, const float* __restrict__ W,
    const float* __restrict__ bias, float* __restrict__ Out)
{
  __shared__ float As[16][132];
  __shared__ float Bs[16][132];
  const int tid = threadIdx.x;
  const int m0 = blockIdx.x * 128;
  const int j0 = blockIdx.y * 128;
  const int tm = (tid >> 4) & 15;
  const int tn = tid & 15;
  const int lk = (tid & 3) << 2;
  const int lr = tid >> 2;
  float acc[2][2][4][4];
  #pragma unroll
  for (int i2=0;i2<2;++i2)
    #pragma unroll
    for (int j2=0;j2<2;++j2)
      #pragma unroll
      for (int i=0;i<4;++i)
        #pragma unroll
        for (int j=0;j<4;++j) acc[i2][j2][i][j] = 0.f;

  const float* xp = X + (size_t)(m0 + lr)*C_ + lk;
  const float* wp = W + (size_t)(j0 + lr)*C_ + lk;

  for (int k0 = 0; k0 < C_; k0 += 16) {
    #pragma unroll
    for (int p = 0; p < 2; ++p) {
      float4 a4 = *reinterpret_cast<const float4*>(xp + k0 + (size_t)p*64*C_);
      float4 b4 = *reinterpret_cast<const float4*>(wp + k0 + (size_t)p*64*C_);
      int row = lr + p*64;
      As[lk+0][row]=a4.x; As[lk+1][row]=a4.y; As[lk+2][row]=a4.z; As[lk+3][row]=a4.w;
      Bs[lk+0][row]=b4.x; Bs[lk+1][row]=b4.y; Bs[lk+2][row]=b4.z; Bs[lk+3][row]=b4.w;
    }
    __syncthreads();
    #pragma unroll
    for (int kk = 0; kk < 16; ++kk) {
      float a[2][4], b[2][4];
      #pragma unroll
      for (int h2 = 0; h2 < 2; ++h2) {
        float4 av = *reinterpret_cast<const float4*>(&As[kk][h2*64 + tm*4]);
        a[h2][0]=av.x; a[h2][1]=av.y; a[h2][2]=av.z; a[h2][3]=av.w;
        float4 bv = *reinterpret_cast<const float4*>(&Bs[kk][h2*64 + tn*4]);
        b[h2][0]=bv.x; b[h2][1]=bv.y; b[h2][2]=bv.z; b[h2][3]=bv.w;
      }
      #pragma unroll
      for (int i2=0;i2<2;++i2)
        #pragma unroll
        for (int j2=0;j2<2;++j2)
          #pragma unroll
          for (int i=0;i<4;++i)
            #pragma unroll
            for (int j=0;j<4;++j)
              acc[i2][j2][i][j] += a[i2][i]*b[j2][j];
    }
    __syncthreads();
  }
  #pragma unroll
  for (int i2=0;i2<2;++i2) {
    #pragma unroll
    for (int i=0;i<4;++i) {
      int m = m0 + i2*64 + tm*4 + i;
      #pragma unroll
      for (int j2=0;j2<2;++j2) {
        #pragma unroll
        for (int j=0;j<4;++j) {
          int col = j0 + j2*64 + tn*4 + j;
          Out[(size_t)m*C_ + col] = acc[i2][j2][i][j] + bias[col];
        }
      }
    }
  }
}

// ---------- agent token pooling: 2x2 mean of q spatial -> (B,H,A,D) ----------
__global__ void k_pool(const float* __restrict__ Q, float* __restrict__ AG) {
  int idx = blockIdx.x*256 + threadIdx.x;
  if (idx >= B_*H_*A_*D_) return;
  int d = idx & 31;
  int a = (idx >> 5) % A_;
  int bh = idx / (A_*D_);
  int ar = a / 7, ac2 = a % 7;
  int n00 = 1 + (ar*2)*14 + ac2*2;
  const float* qb = Q + ((size_t)bh*N_)*D_ + d;
  float s = qb[(size_t)n00*D_] + qb[(size_t)(n00+1)*D_]
          + qb[(size_t)(n00+14)*D_] + qb[(size_t)(n00+15)*D_];
  AG[idx] = 0.25f*s;
}

// ---------- agent attention: softmax_n(ag*K^T + pos_bias), writes rep + agent_v ----------
// one lane per agent row a (49 of 64 lanes active), flash-style exact online softmax
__global__ __launch_bounds__(64) void k_agent_attn(
    const float* __restrict__ Kx, const float* __restrict__ Vx,
    const float* __restrict__ AG, const float* __restrict__ PB,
    float* __restrict__ REP, float* __restrict__ AV)
{
  const int bh = blockIdx.x;
  const int h = bh % H_;
  const int a = threadIdx.x;
  if (a >= A_) return;
  const float* kp  = Kx + (size_t)bh*N_*D_;   // wave-uniform rows -> scalar loads
  const float* vp  = Vx + (size_t)bh*N_*D_;
  const float* pbp = PB + ((size_t)h*A_ + a)*N_;
  float agr[D_];
  {
    const float4* agp = reinterpret_cast<const float4*>(AG + ((size_t)bh*A_ + a)*D_);
    #pragma unroll
    for (int d4 = 0; d4 < 8; ++d4) {
      float4 t = agp[d4];
      agr[d4*4+0]=t.x; agr[d4*4+1]=t.y; agr[d4*4+2]=t.z; agr[d4*4+3]=t.w;
    }
  }
  // pass 1: exact online max & denom
  float m = -1e30f, l = 0.f;
  for (int n = 0; n < N_; ++n) {
    float s = 0.f;
    #pragma unroll
    for (int d = 0; d < D_; ++d) s += agr[d]*kp[n*D_ + d];
    s = s*SCALE_ + pbp[n];
    float mn = fmaxf(m, s);
    l = l*expf(m - mn) + expf(s - mn);
    m = mn;
  }
  const float inv = 1.f/l;
  // pass 2: normalized attn -> rep output, and PV accumulation
  float o[D_];
  #pragma unroll
  for (int d = 0; d < D_; ++d) o[d] = 0.f;
  float* repp = REP + ((size_t)bh*A_ + a)*N_;
  for (int n4 = 0; n4 < 49; ++n4) {
    float at[4];
    #pragma unroll
    for (int r = 0; r < 4; ++r) {
      const int n = n4*4 + r;
      float s = 0.f;
      #pragma unroll
      for (int d = 0; d < D_; ++d) s += agr[d]*kp[n*D_ + d];
      s = s*SCALE_ + pbp[n];
      float e = expf(s - m)*inv;
      at[r] = e;
      #pragma unroll
      for (int d = 0; d < D_; ++d) o[d] += e*vp[n*D_ + d];
    }
    F4U w4; w4.x = at[0]; w4.y = at[1]; w4.z = at[2]; w4.w = at[3];
    *reinterpret_cast<F4U*>(repp + n4*4) = w4;
  }
  { // n = 196 tail
    const int n = 196;
    float s = 0.f;
    #pragma unroll
    for (int d = 0; d < D_; ++d) s += agr[d]*kp[n*D_ + d];
    s = s*SCALE_ + pbp[n];
    float e = expf(s - m)*inv;
    repp[n] = e;
    #pragma unroll
    for (int d = 0; d < D_; ++d) o[d] += e*vp[n*D_ + d];
  }
  float* avp = AV + ((size_t)bh*A_ + a)*D_;
  #pragma unroll
  for (int d4 = 0; d4 < 8; ++d4)
    reinterpret_cast<float4*>(avp)[d4] = make_float4(o[d4*4], o[d4*4+1], o[d4*4+2], o[d4*4+3]);
}

// ---------- q attention: softmax_a(q*ag^T + agent_bias) @ agent_v, one thread per token ----------
__global__ __launch_bounds__(256) void k_q_attn(
    const float* __restrict__ Q, const float* __restrict__ AG,
    const float* __restrict__ AV, const float* __restrict__ AB,
    float* __restrict__ OP)
{
  const int bh = blockIdx.x;
  const int b = bh / H_, h = bh % H_;
  const int n = threadIdx.x;
  if (n >= N_) return;
  float q[D_];
  {
    const float4* qp = reinterpret_cast<const float4*>(Q + ((size_t)bh*N_ + n)*D_);
    #pragma unroll
    for (int d4 = 0; d4 < 8; ++d4) {
      float4 t = qp[d4];
      q[d4*4+0]=t.x; q[d4*4+1]=t.y; q[d4*4+2]=t.z; q[d4*4+3]=t.w;
    }
  }
  const float* agp = AG + (size_t)bh*A_*D_;   // wave-uniform -> scalar loads
  const float* avp = AV + (size_t)bh*A_*D_;
  const float* abp = AB + ((size_t)h*N_ + n)*A_;
  float m = -1e30f, l = 0.f;
  for (int a = 0; a < A_; ++a) {
    float s = 0.f;
    #pragma unroll
    for (int d = 0; d < D_; ++d) s += q[d]*agp[a*D_ + d];
    s = s*SCALE_ + abp[a];
    float mn = fmaxf(m, s);
    l = l*expf(m - mn) + expf(s - mn);
    m = mn;
  }
  const float inv = 1.f/l;
  float o[D_];
  #pragma unroll
  for (int d = 0; d < D_; ++d) o[d] = 0.f;
  for (int a = 0; a < A_; ++a) {
    float s = 0.f;
    #pragma unroll
    for (int d = 0; d < D_; ++d) s += q[d]*agp[a*D_ + d];
    s = s*SCALE_ + abp[a];
    float e = expf(s - m)*inv;
    #pragma unroll
    for (int d = 0; d < D_; ++d) o[d] += e*avp[a*D_ + d];
  }
  float* op = OP + ((size_t)b*N_ + n)*C_ + h*D_;
  #pragma unroll
  for (int d4 = 0; d4 < 8; ++d4)
    reinterpret_cast<float4*>(op)[d4] = make_float4(o[d4*4], o[d4*4+1], o[d4*4+2], o[d4*4+3]);
}

// ---------- depthwise 3x3 conv on v spatial, accumulate into pre-proj out ----------
__global__ void k_dwc(const float* __restrict__ V, const float* __restrict__ WD,
                      const float* __restrict__ BD, float* __restrict__ OP)
{
  int idx = blockIdx.x*256 + threadIdx.x;
  if (idx >= B_*196*C_) return;
  int c = idx % C_;
  int t = (idx / C_) % 196;
  int b = idx / (C_*196);
  int i = t / 14, j = t % 14;
  const float* vb = V + (((size_t)b*H_ + (c>>5))*N_)*D_ + (c&31);
  const float* wd = WD + c*9;
  float acc = BD[c];
  #pragma unroll
  for (int ki = 0; ki < 3; ++ki) {
    int ii = i + ki - 1;
    if (ii < 0 || ii > 13) continue;
    #pragma unroll
    for (int kj = 0; kj < 3; ++kj) {
      int jj = j + kj - 1;
      if (jj < 0 || jj > 13) continue;
      acc += vb[(size_t)(1 + ii*14 + jj)*D_] * wd[ki*3 + kj];
    }
  }
  OP[((size_t)b*N_ + 1 + t)*C_ + c] += acc;
}

extern "C" void kernel_launch(void* const* d_in, const int* in_sizes, int n_in,
                              void* d_out, int out_size, void* d_ws, size_t ws_size,
                              hipStream_t stream)
{
  const float* x       = (const float*)d_in[0];
  const float* w_qkv   = (const float*)d_in[1];
  const float* w_proj  = (const float*)d_in[2];
  const float* b_proj  = (const float*)d_in[3];
  const float* w_dwc   = (const float*)d_in[4];
  const float* b_dwc   = (const float*)d_in[5];
  const float* an_bias = (const float*)d_in[6];
  const float* na_bias = (const float*)d_in[7];
  const float* ah_bias = (const float*)d_in[8];
  const float* aw_bias = (const float*)d_in[9];
  const float* ha_bias = (const float*)d_in[10];
  const float* wa_bias = (const float*)d_in[11];
  const float* ac_bias = (const float*)d_in[12];
  const float* ca_bias = (const float*)d_in[13];

  float* outp = (float*)d_out;                       // (B,N,C) fp32
  float* rep  = outp + (size_t)B_*N_*C_;             // (B,H,A,N) fp32

  float* ws = (float*)d_ws;                          // ~698 MB used
  const size_t SZ_QKV = (size_t)B_*H_*N_*D_;         // 38,731,776
  const size_t SZ_AG  = (size_t)B_*H_*A_*D_;         // 9,633,792
  float* Qb  = ws;
  float* Kb  = Qb  + SZ_QKV;
  float* Vb  = Kb  + SZ_QKV;
  float* AGb = Vb  + SZ_QKV;
  float* AVb = AGb + SZ_AG;
  float* OPb = AVb + SZ_AG;
  float* PBb = OPb + SZ_QKV;
  float* ABb = PBb + (size_t)H_*A_*N_;

  k_pos_bias  <<<dim3((H_*A_*N_ + 255)/256), dim3(256), 0, stream>>>(an_bias, ah_bias, aw_bias, ac_bias, PBb);
  k_agent_bias<<<dim3((H_*N_*A_ + 255)/256), dim3(256), 0, stream>>>(na_bias, ha_bias, wa_bias, ca_bias, ABb);
  k_gemm_qkv  <<<dim3(M_TOT/128, 9), dim3(256), 0, stream>>>(x, w_qkv, Qb, Kb, Vb);
  k_pool      <<<dim3((B_*H_*A_*D_ + 255)/256), dim3(256), 0, stream>>>(Qb, AGb);
  k_agent_attn<<<dim3(B_*H_), dim3(64), 0, stream>>>(Kb, Vb, AGb, PBb, rep, AVb);
  k_q_attn    <<<dim3(B_*H_), dim3(256), 0, stream>>>(Qb, AGb, AVb, ABb, OPb);
  k_dwc       <<<dim3((B_*196*C_ + 255)/256), dim3(256), 0, stream>>>(Vb, w_dwc, b_dwc, OPb);
  k_gemm_proj <<<dim3(M_TOT/128, 3), dim3(256), 0, stream>>>(OPb, w_proj, b_proj, outp);
}

// Round 3
// 2232.900 us; speedup vs baseline: 1.5634x; 1.5634x over previous
//
#include <hip/hip_runtime.h>
#include <cstddef>

#define B_ 512
#define N_ 197
#define C_ 384
#define H_ 12
#define D_ 32
#define A_ 49
#define K3 1152
#define SCALE_ 0.17677669529663687f   // 32^-0.5
#define M_TOT (B_*N_)                 // 100864

typedef __attribute__((ext_vector_type(4))) float f32x4;
typedef __attribute__((ext_vector_type(8))) short bf16x8;

// 16B store with only 4B alignment guarantee (rep rows have odd stride 197)
struct __attribute__((aligned(4))) F4U { float x, y, z, w; };

__device__ __forceinline__ ushort f2bf(float f) {
  uint u = __float_as_uint(f);
  u += 0x7fff + ((u >> 16) & 1);          // round-to-nearest-even
  return (ushort)(u >> 16);
}

__device__ __forceinline__ void gl_lds16(const void* g, void* l) {
  __builtin_amdgcn_global_load_lds(
      (const __attribute__((address_space(1))) unsigned int*)g,
      (__attribute__((address_space(3))) unsigned int*)l, 16, 0, 0);
}

// ---------- fp32 -> bf16 conversion (float4 in, ushort4 out) ----------
__global__ void k_cvt(const float* __restrict__ src, ushort* __restrict__ dst, int n4) {
  int i = blockIdx.x*256 + threadIdx.x;
  if (i >= n4) return;
  float4 v = reinterpret_cast<const float4*>(src)[i];
  ushort4 o; o.x=f2bf(v.x); o.y=f2bf(v.y); o.z=f2bf(v.z); o.w=f2bf(v.w);
  reinterpret_cast<ushort4*>(dst)[i] = o;
}

// ---------- bilinear 7x7 -> 14x14 (jax.image.resize half-pixel semantics) ----------
__device__ __forceinline__ float bilin7(const float* __restrict__ s, int i, int j) {
  float sy = 0.5f*(float)i - 0.25f;
  float sx = 0.5f*(float)j - 0.25f;
  float fy0 = floorf(sy), fx0 = floorf(sx);
  float fy = sy - fy0, fx = sx - fx0;
  int y0 = (int)fy0, x0 = (int)fx0;
  int y1 = y0 + 1, x1 = x0 + 1;
  y0 = min(max(y0, 0), 6); y1 = min(max(y1, 0), 6);
  x0 = min(max(x0, 0), 6); x1 = min(max(x1, 0), 6);
  float v00 = s[y0*7+x0], v01 = s[y0*7+x1], v10 = s[y1*7+x0], v11 = s[y1*7+x1];
  float t0 = v00 + (v01 - v00)*fx;
  float t1 = v10 + (v11 - v10)*fx;
  return t0 + (t1 - t0)*fy;
}

__global__ void k_pos_bias(const float* __restrict__ an, const float* __restrict__ ah,
                           const float* __restrict__ aw, const float* __restrict__ ac,
                           float* __restrict__ pb) {
  int idx = blockIdx.x*256 + threadIdx.x;
  if (idx >= H_*A_*N_) return;
  int n = idx % N_;
  int ha = idx / N_;
  float v;
  if (n == 0) v = ac[ha];
  else {
    int t = n - 1, i = t/14, j = t%14;
    v = bilin7(an + (size_t)ha*49, i, j) + ah[ha*14 + i] + aw[ha*14 + j];
  }
  pb[idx] = v;
}

__global__ void k_agent_bias(const float* __restrict__ na, const float* __restrict__ hab,
                             const float* __restrict__ wab, const float* __restrict__ ca,
                             float* __restrict__ ab) {
  int idx = blockIdx.x*256 + threadIdx.x;
  if (idx >= H_*N_*A_) return;
  int a = idx % A_;
  int n = (idx / A_) % N_;
  int h = idx / (A_*N_);
  float v;
  if (n == 0) v = ca[h*A_ + a];
  else {
    int t = n - 1, i = t/14, j = t%14;
    v = bilin7(na + (size_t)(h*A_ + a)*49, i, j) + hab[(h*14 + i)*A_ + a] + wab[(h*14 + j)*A_ + a];
  }
  ab[idx] = v;
}

// ---------- bf16 MFMA GEMM: C[M,N'] = A[M,K] @ B[N',K]^T ----------
// 128x128 tile, 4 waves (each 64x64 = 4x4 frags of 16x16x32), BK=64,
// global_load_lds w=16 (linear dest) + inverse-swizzled source + swizzled ds_read (G4/rule21).
// MODE 0: scatter to Q/K/V (B,H,N,D) fp32.  MODE 1: row-major out + bias.
template<int MODE>
__global__ __launch_bounds__(256) void k_mm(
    const ushort* __restrict__ Am, const ushort* __restrict__ Bm,
    int Kdim, int NB,
    float* __restrict__ O0, float* __restrict__ O1, float* __restrict__ O2,
    const float* __restrict__ bias)
{
  __shared__ ushort lA[128*64];
  __shared__ ushort lB[128*64];
  const int tid = threadIdx.x;
  const int lane = tid & 63;
  const int wv = tid >> 6;

  // bijective XCD swizzle (m204): blocks sharing an A-panel land on one XCD
  const int nwg = gridDim.x;
  const int wg = blockIdx.x;
  const int qq = nwg >> 3, rr = nwg & 7;
  const int xcd = wg & 7, sidx = wg >> 3;
  const int swz = (xcd < rr) ? (xcd*(qq+1) + sidx) : (rr*(qq+1) + (xcd-rr)*qq + sidx);
  const int bx = swz / NB;
  const int by = swz - bx*NB;
  const int m0 = bx * 128;
  const int n0 = by * 128;

  const int wr = wv >> 1, wc = wv & 1;
  f32x4 acc[4][4];
  #pragma unroll
  for (int m=0;m<4;++m)
    #pragma unroll
    for (int n=0;n<4;++n) acc[m][n] = (f32x4){0.f,0.f,0.f,0.f};

  const int srow = wv*8 + (lane>>3);   // row within 32-row staging group
  const int scolb = (lane&7)<<4;       // byte col within 128B row

  for (int kt = 0; kt < Kdim; kt += 64) {
    #pragma unroll
    for (int i = 0; i < 4; ++i) {
      const int rA = i*32 + srow;
      const int src = scolb ^ ((rA&7)<<4);     // inverse-swizzled global source
      gl_lds16(Am + (size_t)(m0+rA)*Kdim + kt + (src>>1), &lA[(i*32 + wv*8)*64]);
      gl_lds16(Bm + (size_t)(n0+rA)*Kdim + kt + (src>>1), &lB[(i*32 + wv*8)*64]);
    }
    __syncthreads();
    #pragma unroll
    for (int kk = 0; kk < 2; ++kk) {
      bf16x8 af[4], bfr[4];
      #pragma unroll
      for (int m = 0; m < 4; ++m) {
        const int ar = wr*64 + m*16 + (lane&15);
        const int ac = (kk*64 + ((lane>>4)<<4)) ^ ((ar&7)<<4);
        af[m] = *reinterpret_cast<const bf16x8*>(reinterpret_cast<const char*>(lA) + ar*128 + ac);
        const int br = wc*64 + m*16 + (lane&15);
        const int bc = (kk*64 + ((lane>>4)<<4)) ^ ((br&7)<<4);
        bfr[m] = *reinterpret_cast<const bf16x8*>(reinterpret_cast<const char*>(lB) + br*128 + bc);
      }
      #pragma unroll
      for (int m = 0; m < 4; ++m)
        #pragma unroll
        for (int n = 0; n < 4; ++n)
          acc[m][n] = __builtin_amdgcn_mfma_f32_16x16x32_bf16(af[m], bfr[n], acc[m][n], 0, 0, 0);
    }
    __syncthreads();
  }

  const int lr4 = (lane>>4) << 2;
  const int lc = lane & 15;
  if (MODE == 0) {
    float* dst = (by < 3) ? O0 : ((by < 6) ? O1 : O2);
    const int cb = (by % 3) * 128 + wc*64;
    #pragma unroll
    for (int m = 0; m < 4; ++m) {
      #pragma unroll
      for (int j = 0; j < 4; ++j) {
        const int gm = m0 + wr*64 + m*16 + lr4 + j;
        const uint bidx = (uint)gm / 197u;
        const uint nn = (uint)gm - bidx*197u;
        #pragma unroll
        for (int n = 0; n < 4; ++n) {
          const int cc = cb + n*16 + lc;
          dst[(((size_t)bidx*H_ + (cc>>5))*N_ + nn)*D_ + (cc&31)] = acc[m][n][j];
        }
      }
    }
  } else {
    #pragma unroll
    for (int m = 0; m < 4; ++m) {
      #pragma unroll
      for (int j = 0; j < 4; ++j) {
        const int gm = m0 + wr*64 + m*16 + lr4 + j;
        #pragma unroll
        for (int n = 0; n < 4; ++n) {
          const int gc = n0 + wc*64 + n*16 + lc;
          O0[(size_t)gm*C_ + gc] = acc[m][n][j] + bias[gc];
        }
      }
    }
  }
}

// ---------- agent token pooling: 2x2 mean of q spatial -> (B,H,A,D) ----------
__global__ void k_pool(const float* __restrict__ Q, float* __restrict__ AG) {
  int idx = blockIdx.x*256 + threadIdx.x;
  if (idx >= B_*H_*A_*D_) return;
  int d = idx & 31;
  int a = (idx >> 5) % A_;
  int bh = idx / (A_*D_);
  int ar = a / 7, ac2 = a % 7;
  int n00 = 1 + (ar*2)*14 + ac2*2;
  const float* qb = Q + ((size_t)bh*N_)*D_ + d;
  float s = qb[(size_t)n00*D_] + qb[(size_t)(n00+1)*D_]
          + qb[(size_t)(n00+14)*D_] + qb[(size_t)(n00+15)*D_];
  AG[idx] = 0.25f*s;
}

// ---------- agent attention: softmax_n(ag*K^T + pos_bias), writes rep + agent_v ----------
__global__ __launch_bounds__(64) void k_agent_attn(
    const float* __restrict__ Kx, const float* __restrict__ Vx,
    const float* __restrict__ AG, const float* __restrict__ PB,
    float* __restrict__ REP, float* __restrict__ AV)
{
  const int bh = blockIdx.x;
  const int h = bh % H_;
  const int a = threadIdx.x;
  if (a >= A_) return;
  const float* kp  = Kx + (size_t)bh*N_*D_;
  const float* vp  = Vx + (size_t)bh*N_*D_;
  const float* pbp = PB + ((size_t)h*A_ + a)*N_;
  float agr[D_];
  {
    const float4* agp = reinterpret_cast<const float4*>(AG + ((size_t)bh*A_ + a)*D_);
    #pragma unroll
    for (int d4 = 0; d4 < 8; ++d4) {
      float4 t = agp[d4];
      agr[d4*4+0]=t.x; agr[d4*4+1]=t.y; agr[d4*4+2]=t.z; agr[d4*4+3]=t.w;
    }
  }
  float m = -1e30f, l = 0.f;
  for (int n = 0; n < N_; ++n) {
    float s = 0.f;
    #pragma unroll
    for (int d = 0; d < D_; ++d) s += agr[d]*kp[n*D_ + d];
    s = s*SCALE_ + pbp[n];
    float mn = fmaxf(m, s);
    l = l*expf(m - mn) + expf(s - mn);
    m = mn;
  }
  const float inv = 1.f/l;
  float o[D_];
  #pragma unroll
  for (int d = 0; d < D_; ++d) o[d] = 0.f;
  float* repp = REP + ((size_t)bh*A_ + a)*N_;
  for (int n4 = 0; n4 < 49; ++n4) {
    float at[4];
    #pragma unroll
    for (int r = 0; r < 4; ++r) {
      const int n = n4*4 + r;
      float s = 0.f;
      #pragma unroll
      for (int d = 0; d < D_; ++d) s += agr[d]*kp[n*D_ + d];
      s = s*SCALE_ + pbp[n];
      float e = expf(s - m)*inv;
      at[r] = e;
      #pragma unroll
      for (int d = 0; d < D_; ++d) o[d] += e*vp[n*D_ + d];
    }
    F4U w4; w4.x = at[0]; w4.y = at[1]; w4.z = at[2]; w4.w = at[3];
    *reinterpret_cast<F4U*>(repp + n4*4) = w4;
  }
  {
    const int n = 196;
    float s = 0.f;
    #pragma unroll
    for (int d = 0; d < D_; ++d) s += agr[d]*kp[n*D_ + d];
    s = s*SCALE_ + pbp[n];
    float e = expf(s - m)*inv;
    repp[n] = e;
    #pragma unroll
    for (int d = 0; d < D_; ++d) o[d] += e*vp[n*D_ + d];
  }
  float* avp = AV + ((size_t)bh*A_ + a)*D_;
  #pragma unroll
  for (int d4 = 0; d4 < 8; ++d4)
    reinterpret_cast<float4*>(avp)[d4] = make_float4(o[d4*4], o[d4*4+1], o[d4*4+2], o[d4*4+3]);
}

// ---------- q attention + fused depthwise 3x3 conv, writes OP (bf16) ----------
__global__ __launch_bounds__(256) void k_q_attn_dwc(
    const float* __restrict__ Q, const float* __restrict__ AG,
    const float* __restrict__ AV, const float* __restrict__ AB,
    const float* __restrict__ V, const float* __restrict__ WD,
    const float* __restrict__ BD, ushort* __restrict__ OP)
{
  __shared__ float swd[288];
  __shared__ float sbd[32];
  const int bh = blockIdx.x;
  const int b = bh / H_, h = bh - b*H_;
  const int tid = threadIdx.x;
  for (int i = tid; i < 288; i += 256) swd[i] = WD[h*288 + i]; // (c,1,3,3): c=h*32+i/9, tap=i%9
  if (tid < 32) sbd[tid] = BD[h*32 + tid];
  __syncthreads();
  const int n = tid;
  if (n >= N_) return;
  float q[D_];
  {
    const float4* qp = reinterpret_cast<const float4*>(Q + ((size_t)bh*N_ + n)*D_);
    #pragma unroll
    for (int d4 = 0; d4 < 8; ++d4) {
      float4 t = qp[d4];
      q[d4*4+0]=t.x; q[d4*4+1]=t.y; q[d4*4+2]=t.z; q[d4*4+3]=t.w;
    }
  }
  const float* agp = AG + (size_t)bh*A_*D_;
  const float* avp = AV + (size_t)bh*A_*D_;
  const float* abp = AB + ((size_t)h*N_ + n)*A_;
  float m = -1e30f, l = 0.f;
  for (int a = 0; a < A_; ++a) {
    float s = 0.f;
    #pragma unroll
    for (int d = 0; d < D_; ++d) s += q[d]*agp[a*D_ + d];
    s = s*SCALE_ + abp[a];
    float mn = fmaxf(m, s);
    l = l*expf(m - mn) + expf(s - mn);
    m = mn;
  }
  const float inv = 1.f/l;
  float oo[D_];
  #pragma unroll
  for (int d = 0; d < D_; ++d) oo[d] = 0.f;
  for (int a = 0; a < A_; ++a) {
    float s = 0.f;
    #pragma unroll
    for (int d = 0; d < D_; ++d) s += q[d]*agp[a*D_ + d];
    s = s*SCALE_ + abp[a];
    float e = expf(s - m)*inv;
    #pragma unroll
    for (int d = 0; d < D_; ++d) oo[d] += e*avp[a*D_ + d];
  }
  if (n > 0) {   // depthwise 3x3 on v spatial, channels h*32..h*32+31
    const int t = n - 1, i = t/14, j = t - (t/14)*14;
    #pragma unroll
    for (int ki = 0; ki < 3; ++ki) {
      const int ii = i + ki - 1;
      if (ii < 0 || ii > 13) continue;
      #pragma unroll
      for (int kj = 0; kj < 3; ++kj) {
        const int jj = j + kj - 1;
        if (jj < 0 || jj > 13) continue;
        const int tap = ki*3 + kj;
        const float* vr = V + ((size_t)bh*N_ + (1 + ii*14 + jj))*D_;
        #pragma unroll
        for (int d4 = 0; d4 < 8; ++d4) {
          float4 vv = reinterpret_cast<const float4*>(vr)[d4];
          oo[d4*4+0] += swd[(d4*4+0)*9 + tap]*vv.x;
          oo[d4*4+1] += swd[(d4*4+1)*9 + tap]*vv.y;
          oo[d4*4+2] += swd[(d4*4+2)*9 + tap]*vv.z;
          oo[d4*4+3] += swd[(d4*4+3)*9 + tap]*vv.w;
        }
      }
    }
    #pragma unroll
    for (int d = 0; d < D_; ++d) oo[d] += sbd[d];
  }
  ushort* opp = OP + ((size_t)(b*N_ + n))*C_ + h*D_;
  #pragma unroll
  for (int s4 = 0; s4 < 8; ++s4) {
    ushort4 u;
    u.x = f2bf(oo[s4*4+0]); u.y = f2bf(oo[s4*4+1]);
    u.z = f2bf(oo[s4*4+2]); u.w = f2bf(oo[s4*4+3]);
    reinterpret_cast<ushort4*>(opp)[s4] = u;
  }
}

extern "C" void kernel_launch(void* const* d_in, const int* in_sizes, int n_in,
                              void* d_out, int out_size, void* d_ws, size_t ws_size,
                              hipStream_t stream)
{
  const float* x       = (const float*)d_in[0];
  const float* w_qkv   = (const float*)d_in[1];
  const float* w_proj  = (const float*)d_in[2];
  const float* b_proj  = (const float*)d_in[3];
  const float* w_dwc   = (const float*)d_in[4];
  const float* b_dwc   = (const float*)d_in[5];
  const float* an_bias = (const float*)d_in[6];
  const float* na_bias = (const float*)d_in[7];
  const float* ah_bias = (const float*)d_in[8];
  const float* aw_bias = (const float*)d_in[9];
  const float* ha_bias = (const float*)d_in[10];
  const float* wa_bias = (const float*)d_in[11];
  const float* ac_bias = (const float*)d_in[12];
  const float* ca_bias = (const float*)d_in[13];

  float* outp = (float*)d_out;                       // (B,N,C) fp32
  float* rep  = outp + (size_t)B_*N_*C_;             // (B,H,A,N) fp32

  const size_t SZ_QKV = (size_t)B_*H_*N_*D_;         // 38,731,776
  const size_t SZ_AG  = (size_t)B_*H_*A_*D_;         // 9,633,792
  char* w = (char*)d_ws;
  float*  Qb     = (float*)w;  w += SZ_QKV*4;
  float*  Kb     = (float*)w;  w += SZ_QKV*4;
  float*  Vb     = (float*)w;  w += SZ_QKV*4;
  float*  AGb    = (float*)w;  w += SZ_AG*4;
  float*  AVb    = (float*)w;  w += SZ_AG*4;
  float*  PBb    = (float*)w;  w += (size_t)H_*A_*N_*4;
  float*  ABb    = (float*)w;  w += (size_t)H_*N_*A_*4;
  ushort* Xbf    = (ushort*)w; w += SZ_QKV*2;
  ushort* OPbf   = (ushort*)w; w += SZ_QKV*2;
  ushort* Wqkvb  = (ushort*)w; w += (size_t)K3*C_*2;
  ushort* Wprojb = (ushort*)w; w += (size_t)C_*C_*2;

  // conversions
  k_cvt<<<dim3((int)(SZ_QKV/4/256)), dim3(256), 0, stream>>>(x, Xbf, (int)(SZ_QKV/4));
  k_cvt<<<dim3(K3*C_/4/256), dim3(256), 0, stream>>>(w_qkv, Wqkvb, K3*C_/4);
  k_cvt<<<dim3(C_*C_/4/256), dim3(256), 0, stream>>>(w_proj, Wprojb, C_*C_/4);
  // biases
  k_pos_bias  <<<dim3((H_*A_*N_ + 255)/256), dim3(256), 0, stream>>>(an_bias, ah_bias, aw_bias, ac_bias, PBb);
  k_agent_bias<<<dim3((H_*N_*A_ + 255)/256), dim3(256), 0, stream>>>(na_bias, ha_bias, wa_bias, ca_bias, ABb);
  // qkv GEMM: (100864 x 384) @ (1152 x 384)^T -> scatter Q/K/V
  k_mm<0><<<dim3((M_TOT/128)*9), dim3(256), 0, stream>>>(Xbf, Wqkvb, C_, 9, Qb, Kb, Vb, nullptr);
  // agent pooling + attentions (+fused dwc)
  k_pool      <<<dim3((int)((B_*H_*A_*D_ + 255)/256)), dim3(256), 0, stream>>>(Qb, AGb);
  k_agent_attn<<<dim3(B_*H_), dim3(64), 0, stream>>>(Kb, Vb, AGb, PBb, rep, AVb);
  k_q_attn_dwc<<<dim3(B_*H_), dim3(256), 0, stream>>>(Qb, AGb, AVb, ABb, Vb, w_dwc, b_dwc, OPbf);
  // proj GEMM: (100864 x 384) @ (384 x 384)^T + bias -> out
  k_mm<1><<<dim3((M_TOT/128)*3), dim3(256), 0, stream>>>(OPbf, Wprojb, C_, 3, outp, nullptr, nullptr, b_proj);
}

// Round 6
// 1553.195 us; speedup vs baseline: 2.2476x; 1.4376x over previous
//
#include <hip/hip_runtime.h>
#include <cstddef>

#define B_ 512
#define N_ 197
#define C_ 384
#define H_ 12
#define D_ 32
#define A_ 49
#define K3 1152
#define SCALE_ 0.17677669529663687f   // 32^-0.5
#define M_TOT (B_*N_)                 // 100864
#define VROW 36                        // Vs row stride (floats): 16B-aligned rows
#define SROW 198                       // S row stride (floats)

typedef __attribute__((ext_vector_type(4))) float f32x4;
typedef __attribute__((ext_vector_type(8))) short bf16x8;

__device__ __forceinline__ ushort f2bf(float f) {
  uint u = __float_as_uint(f);
  u += 0x7fff + ((u >> 16) & 1);          // round-to-nearest-even
  return (ushort)(u >> 16);
}

__device__ __forceinline__ void gl_lds16(const void* g, void* l) {
  __builtin_amdgcn_global_load_lds(
      (const __attribute__((address_space(1))) unsigned int*)g,
      (__attribute__((address_space(3))) unsigned int*)l, 16, 0, 0);
}

// ---------- fp32 -> bf16 conversion ----------
__global__ void k_cvt(const float* __restrict__ src, ushort* __restrict__ dst, int n4) {
  int i = blockIdx.x*256 + threadIdx.x;
  if (i >= n4) return;
  float4 v = reinterpret_cast<const float4*>(src)[i];
  ushort4 o; o.x=f2bf(v.x); o.y=f2bf(v.y); o.z=f2bf(v.z); o.w=f2bf(v.w);
  reinterpret_cast<ushort4*>(dst)[i] = o;
}

// ---------- bilinear 7x7 -> 14x14 (jax.image.resize half-pixel semantics) ----------
__device__ __forceinline__ float bilin7(const float* __restrict__ s, int i, int j) {
  float sy = 0.5f*(float)i - 0.25f;
  float sx = 0.5f*(float)j - 0.25f;
  float fy0 = floorf(sy), fx0 = floorf(sx);
  float fy = sy - fy0, fx = sx - fx0;
  int y0 = (int)fy0, x0 = (int)fx0;
  int y1 = y0 + 1, x1 = x0 + 1;
  y0 = min(max(y0, 0), 6); y1 = min(max(y1, 0), 6);
  x0 = min(max(x0, 0), 6); x1 = min(max(x1, 0), 6);
  float v00 = s[y0*7+x0], v01 = s[y0*7+x1], v10 = s[y1*7+x0], v11 = s[y1*7+x1];
  float t0 = v00 + (v01 - v00)*fx;
  float t1 = v10 + (v11 - v10)*fx;
  return t0 + (t1 - t0)*fy;
}

// pos_bias (H,A,197): [ac | resize(an)+ah+aw]
__global__ void k_pos_bias(const float* __restrict__ an, const float* __restrict__ ah,
                           const float* __restrict__ aw, const float* __restrict__ ac,
                           float* __restrict__ pb) {
  int idx = blockIdx.x*256 + threadIdx.x;
  if (idx >= H_*A_*N_) return;
  int n = idx % N_;
  int ha = idx / N_;
  float v;
  if (n == 0) v = ac[ha];
  else {
    int t = n - 1, i = t/14, j = t%14;
    v = bilin7(an + (size_t)ha*49, i, j) + ah[ha*14 + i] + aw[ha*14 + j];
  }
  pb[idx] = v;
}

// agent_bias TRANSPOSED (H,A,197): abt[h][a][n]; row n==0 from ca
__global__ void k_agent_bias_t(const float* __restrict__ na, const float* __restrict__ hab,
                               const float* __restrict__ wab, const float* __restrict__ ca,
                               float* __restrict__ abt) {
  int idx = blockIdx.x*256 + threadIdx.x;
  if (idx >= H_*A_*N_) return;
  int n = idx % N_;
  int a = (idx / N_) % A_;
  int h = idx / (A_*N_);
  float v;
  if (n == 0) v = ca[h*A_ + a];
  else {
    int t = n - 1, i = t/14, j = t%14;
    v = bilin7(na + (size_t)(h*A_ + a)*49, i, j) + hab[(h*14 + i)*A_ + a] + wab[(h*14 + j)*A_ + a];
  }
  abt[idx] = v;
}

// ---------- bf16 MFMA GEMM (verified passing in round 3) ----------
template<int MODE>
__global__ __launch_bounds__(256) void k_mm(
    const ushort* __restrict__ Am, const ushort* __restrict__ Bm,
    int Kdim, int NB,
    float* __restrict__ O0, float* __restrict__ O1, float* __restrict__ O2,
    const float* __restrict__ bias)
{
  __shared__ ushort lA[128*64];
  __shared__ ushort lB[128*64];
  const int tid = threadIdx.x;
  const int lane = tid & 63;
  const int wv = tid >> 6;

  const int nwg = gridDim.x;
  const int wg = blockIdx.x;
  const int qq = nwg >> 3, rr = nwg & 7;
  const int xcd = wg & 7, sidx = wg >> 3;
  const int swz = (xcd < rr) ? (xcd*(qq+1) + sidx) : (rr*(qq+1) + (xcd-rr)*qq + sidx);
  const int bx = swz / NB;
  const int by = swz - bx*NB;
  const int m0 = bx * 128;
  const int n0 = by * 128;

  const int wr = wv >> 1, wc = wv & 1;
  f32x4 acc[4][4];
  #pragma unroll
  for (int m=0;m<4;++m)
    #pragma unroll
    for (int n=0;n<4;++n) acc[m][n] = (f32x4){0.f,0.f,0.f,0.f};

  const int srow = wv*8 + (lane>>3);
  const int scolb = (lane&7)<<4;

  for (int kt = 0; kt < Kdim; kt += 64) {
    #pragma unroll
    for (int i = 0; i < 4; ++i) {
      const int rA = i*32 + srow;
      const int src = scolb ^ ((rA&7)<<4);
      gl_lds16(Am + (size_t)(m0+rA)*Kdim + kt + (src>>1), &lA[(i*32 + wv*8)*64]);
      gl_lds16(Bm + (size_t)(n0+rA)*Kdim + kt + (src>>1), &lB[(i*32 + wv*8)*64]);
    }
    __syncthreads();
    #pragma unroll
    for (int kk = 0; kk < 2; ++kk) {
      bf16x8 af[4], bfr[4];
      #pragma unroll
      for (int m = 0; m < 4; ++m) {
        const int ar = wr*64 + m*16 + (lane&15);
        const int ac = (kk*64 + ((lane>>4)<<4)) ^ ((ar&7)<<4);
        af[m] = *reinterpret_cast<const bf16x8*>(reinterpret_cast<const char*>(lA) + ar*128 + ac);
        const int br = wc*64 + m*16 + (lane&15);
        const int bc = (kk*64 + ((lane>>4)<<4)) ^ ((br&7)<<4);
        bfr[m] = *reinterpret_cast<const bf16x8*>(reinterpret_cast<const char*>(lB) + br*128 + bc);
      }
      #pragma unroll
      for (int m = 0; m < 4; ++m)
        #pragma unroll
        for (int n = 0; n < 4; ++n)
          acc[m][n] = __builtin_amdgcn_mfma_f32_16x16x32_bf16(af[m], bfr[n], acc[m][n], 0, 0, 0);
    }
    __syncthreads();
  }

  const int lr4 = (lane>>4) << 2;
  const int lc = lane & 15;
  if (MODE == 0) {
    float* dst = (by < 3) ? O0 : ((by < 6) ? O1 : O2);
    const int cb = (by % 3) * 128 + wc*64;
    #pragma unroll
    for (int m = 0; m < 4; ++m) {
      #pragma unroll
      for (int j = 0; j < 4; ++j) {
        const int gm = m0 + wr*64 + m*16 + lr4 + j;
        const uint bidx = (uint)gm / 197u;
        const uint nn = (uint)gm - bidx*197u;
        #pragma unroll
        for (int n = 0; n < 4; ++n) {
          const int cc = cb + n*16 + lc;
          dst[(((size_t)bidx*H_ + (cc>>5))*N_ + nn)*D_ + (cc&31)] = acc[m][n][j];
        }
      }
    }
  } else {
    #pragma unroll
    for (int m = 0; m < 4; ++m) {
      #pragma unroll
      for (int j = 0; j < 4; ++j) {
        const int gm = m0 + wr*64 + m*16 + lr4 + j;
        #pragma unroll
        for (int n = 0; n < 4; ++n) {
          const int gc = n0 + wc*64 + n*16 + lc;
          O0[(size_t)gm*C_ + gc] = acc[m][n][j] + bias[gc];
        }
      }
    }
  }
}

// ---------- fused attention: pool + agent attn (+rep) + PV + q attn + dwc ----------
// one block per (b,h), 256 threads; K/V/ag/avs/S all LDS-resident.
__global__ __launch_bounds__(256) void k_attn_fused(
    const float* __restrict__ Q, const float* __restrict__ Kx, const float* __restrict__ V,
    const float* __restrict__ PB, const float* __restrict__ ABt,
    const float* __restrict__ WD, const float* __restrict__ BD,
    float* __restrict__ REP, ushort* __restrict__ OP)
{
  __shared__ float ag [A_][D_];     //  6.3 KB
  __shared__ float avs[A_][D_];     //  6.3 KB
  __shared__ float Vs [N_][VROW];   // 28.4 KB
  __shared__ float S  [A_][SROW];   // 38.8 KB
  __shared__ float swd[288];
  __shared__ float sbd[D_];

  const int bh = blockIdx.x;
  const int b = bh / H_, h = bh - b*H_;
  const int tid = threadIdx.x;
  const int lane = tid & 63, wv = tid >> 6;

  for (int i = tid; i < 288; i += 256) swd[i] = WD[h*288 + i];
  if (tid < D_) sbd[tid] = BD[h*D_ + tid];

  // stage V (197x32) into LDS
  const float* vbase = V + (size_t)bh*N_*D_;
  for (int idx = tid; idx < N_*8; idx += 256) {
    const int r = idx >> 3, c4 = idx & 7;
    float4 t = reinterpret_cast<const float4*>(vbase + (size_t)r*D_)[c4];
    Vs[r][c4*4+0]=t.x; Vs[r][c4*4+1]=t.y; Vs[r][c4*4+2]=t.z; Vs[r][c4*4+3]=t.w;
  }
  // agent pooling from Q: ag[a][:] = mean of 2x2 q rows
  const float* qbase = Q + (size_t)bh*N_*D_;
  for (int idx = tid; idx < A_*8; idx += 256) {
    const int a = idx >> 3, c4 = idx & 7;
    const int ar = a/7, ac = a - (a/7)*7;
    const int n00 = 1 + (ar*2)*14 + ac*2;
    float4 r0 = reinterpret_cast<const float4*>(qbase + (size_t)(n00   )*D_)[c4];
    float4 r1 = reinterpret_cast<const float4*>(qbase + (size_t)(n00+ 1)*D_)[c4];
    float4 r2 = reinterpret_cast<const float4*>(qbase + (size_t)(n00+14)*D_)[c4];
    float4 r3 = reinterpret_cast<const float4*>(qbase + (size_t)(n00+15)*D_)[c4];
    ag[a][c4*4+0] = 0.25f*(r0.x+r1.x+r2.x+r3.x);
    ag[a][c4*4+1] = 0.25f*(r0.y+r1.y+r2.y+r3.y);
    ag[a][c4*4+2] = 0.25f*(r0.z+r1.z+r2.z+r3.z);
    ag[a][c4*4+3] = 0.25f*(r0.w+r1.w+r2.w+r3.w);
  }
  __syncthreads();

  // phase A: S[a][n] = SCALE * ag[a]·K[n] + PB[h][a][n]
  if (tid < N_) {
    float kr[D_];
    const float* kb = Kx + ((size_t)bh*N_ + tid)*D_;
    #pragma unroll
    for (int d4 = 0; d4 < 8; ++d4) {
      float4 t = reinterpret_cast<const float4*>(kb)[d4];
      kr[d4*4+0]=t.x*SCALE_; kr[d4*4+1]=t.y*SCALE_; kr[d4*4+2]=t.z*SCALE_; kr[d4*4+3]=t.w*SCALE_;
    }
    const float* pbp = PB + (size_t)h*A_*N_ + tid;
    for (int a = 0; a < A_; ++a) {
      float s = 0.f;
      #pragma unroll
      for (int d4 = 0; d4 < 8; ++d4) {
        float4 av = *reinterpret_cast<const float4*>(&ag[a][d4*4]);
        s += kr[d4*4+0]*av.x + kr[d4*4+1]*av.y + kr[d4*4+2]*av.z + kr[d4*4+3]*av.w;
      }
      S[a][tid] = s + pbp[(size_t)a*N_];
    }
  }
  __syncthreads();

  // row softmax over n (wave per row) -> normalized S + coalesced rep write
  float* repb = REP + (size_t)bh*A_*N_;
  for (int a = wv; a < A_; a += 4) {
    float v0 = S[a][lane];
    float v1 = S[a][lane+64];
    float v2 = S[a][lane+128];
    float v3 = (lane < 5) ? S[a][lane+192] : -1e30f;
    float mx = fmaxf(fmaxf(v0,v1), fmaxf(v2,v3));
    #pragma unroll
    for (int o = 32; o >= 1; o >>= 1) mx = fmaxf(mx, __shfl_xor(mx, o));
    float e0 = __expf(v0-mx), e1 = __expf(v1-mx), e2 = __expf(v2-mx);
    float e3 = (lane < 5) ? __expf(v3-mx) : 0.f;
    float l = e0+e1+e2+e3;
    #pragma unroll
    for (int o = 32; o >= 1; o >>= 1) l += __shfl_xor(l, o);
    const float inv = 1.f/l;
    e0 *= inv; e1 *= inv; e2 *= inv; e3 *= inv;
    S[a][lane]=e0; S[a][lane+64]=e1; S[a][lane+128]=e2;
    if (lane < 5) S[a][lane+192]=e3;
    float* rr = repb + (size_t)a*N_;
    rr[lane]=e0; rr[lane+64]=e1; rr[lane+128]=e2;
    if (lane < 5) rr[lane+192]=e3;
  }
  __syncthreads();

  // PV: avs[a][d] = sum_n S[a][n] * Vs[n][d]; thread = (a, d4)
  {
    const int d4 = tid & 7;            // 16B column group
    const int a0 = tid >> 3;           // 0..31
    #pragma unroll
    for (int half = 0; half < 2; ++half) {
      const int a = half*32 + a0;
      if (a < A_) {
        f32x4 accv = (f32x4){0.f,0.f,0.f,0.f};
        for (int n = 0; n < N_; ++n) {
          const float p = S[a][n];                                    // 2-way-shared b32
          const float4 vv = *reinterpret_cast<const float4*>(&Vs[n][d4*4]);  // broadcast b128
          accv[0] += p*vv.x; accv[1] += p*vv.y; accv[2] += p*vv.z; accv[3] += p*vv.w;
        }
        *reinterpret_cast<f32x4*>(&avs[a][d4*4]) = accv;
      }
    }
  }
  __syncthreads();

  // phase B: q attention (reuse S for scores) + dwc from Vs, write OP bf16
  if (tid < N_) {
    const int n = tid;
    float q[D_];
    {
      const float4* qp = reinterpret_cast<const float4*>(qbase + (size_t)n*D_);
      #pragma unroll
      for (int d4 = 0; d4 < 8; ++d4) {
        float4 t = qp[d4];
        q[d4*4+0]=t.x*SCALE_; q[d4*4+1]=t.y*SCALE_; q[d4*4+2]=t.z*SCALE_; q[d4*4+3]=t.w*SCALE_;
      }
    }
    const float* abp = ABt + (size_t)h*A_*N_ + n;
    for (int a = 0; a < A_; ++a) {
      float s = 0.f;
      #pragma unroll
      for (int d4 = 0; d4 < 8; ++d4) {
        float4 av = *reinterpret_cast<const float4*>(&ag[a][d4*4]);
        s += q[d4*4+0]*av.x + q[d4*4+1]*av.y + q[d4*4+2]*av.z + q[d4*4+3]*av.w;
      }
      S[a][n] = s + abp[(size_t)a*N_];
    }
    float mx = -1e30f;
    for (int a = 0; a < A_; ++a) mx = fmaxf(mx, S[a][n]);
    float l = 0.f;
    for (int a = 0; a < A_; ++a) { float e = __expf(S[a][n]-mx); S[a][n] = e; l += e; }
    const float inv = 1.f/l;
    float oo[D_];
    #pragma unroll
    for (int d = 0; d < D_; ++d) oo[d] = 0.f;
    for (int a = 0; a < A_; ++a) {
      const float p = S[a][n]*inv;
      #pragma unroll
      for (int d4 = 0; d4 < 8; ++d4) {
        float4 av = *reinterpret_cast<const float4*>(&avs[a][d4*4]);
        oo[d4*4+0] += p*av.x; oo[d4*4+1] += p*av.y; oo[d4*4+2] += p*av.z; oo[d4*4+3] += p*av.w;
      }
    }
    if (n > 0) {   // depthwise 3x3 over Vs spatial, channels h*32..h*32+31
      const int t = n - 1, i = t/14, j = t - (t/14)*14;
      #pragma unroll
      for (int ki = 0; ki < 3; ++ki) {
        const int ii = i + ki - 1;
        if (ii < 0 || ii > 13) continue;
        #pragma unroll
        for (int kj = 0; kj < 3; ++kj) {
          const int jj = j + kj - 1;
          if (jj < 0 || jj > 13) continue;
          const int tap = ki*3 + kj;
          const float* vr = &Vs[1 + ii*14 + jj][0];
          #pragma unroll
          for (int d2 = 0; d2 < 16; ++d2) {
            float2 vv = *reinterpret_cast<const float2*>(&vr[d2*2]);
            oo[d2*2+0] += swd[(d2*2+0)*9 + tap]*vv.x;
            oo[d2*2+1] += swd[(d2*2+1)*9 + tap]*vv.y;
          }
        }
      }
      #pragma unroll
      for (int d = 0; d < D_; ++d) oo[d] += sbd[d];
    }
    ushort* opp = OP + ((size_t)(b*N_ + n))*C_ + h*D_;
    #pragma unroll
    for (int s4 = 0; s4 < 8; ++s4) {
      ushort4 u;
      u.x = f2bf(oo[s4*4+0]); u.y = f2bf(oo[s4*4+1]);
      u.z = f2bf(oo[s4*4+2]); u.w = f2bf(oo[s4*4+3]);
      reinterpret_cast<ushort4*>(opp)[s4] = u;
    }
  }
}

extern "C" void kernel_launch(void* const* d_in, const int* in_sizes, int n_in,
                              void* d_out, int out_size, void* d_ws, size_t ws_size,
                              hipStream_t stream)
{
  const float* x       = (const float*)d_in[0];
  const float* w_qkv   = (const float*)d_in[1];
  const float* w_proj  = (const float*)d_in[2];
  const float* b_proj  = (const float*)d_in[3];
  const float* w_dwc   = (const float*)d_in[4];
  const float* b_dwc   = (const float*)d_in[5];
  const float* an_bias = (const float*)d_in[6];
  const float* na_bias = (const float*)d_in[7];
  const float* ah_bias = (const float*)d_in[8];
  const float* aw_bias = (const float*)d_in[9];
  const float* ha_bias = (const float*)d_in[10];
  const float* wa_bias = (const float*)d_in[11];
  const float* ac_bias = (const float*)d_in[12];
  const float* ca_bias = (const float*)d_in[13];

  float* outp = (float*)d_out;                       // (B,N,C) fp32
  float* rep  = outp + (size_t)B_*N_*C_;             // (B,H,A,N) fp32

  const size_t SZ_QKV = (size_t)B_*H_*N_*D_;         // 38,731,776
  char* w = (char*)d_ws;
  float*  Qb     = (float*)w;  w += SZ_QKV*4;
  float*  Kb     = (float*)w;  w += SZ_QKV*4;
  float*  Vb     = (float*)w;  w += SZ_QKV*4;
  float*  PBb    = (float*)w;  w += (size_t)H_*A_*N_*4;
  float*  ABb    = (float*)w;  w += (size_t)H_*A_*N_*4;
  ushort* Xbf    = (ushort*)w; w += SZ_QKV*2;
  ushort* OPbf   = (ushort*)w; w += SZ_QKV*2;
  ushort* Wqkvb  = (ushort*)w; w += (size_t)K3*C_*2;
  ushort* Wprojb = (ushort*)w; w += (size_t)C_*C_*2;

  // conversions
  k_cvt<<<dim3((int)(SZ_QKV/4/256)), dim3(256), 0, stream>>>(x, Xbf, (int)(SZ_QKV/4));
  k_cvt<<<dim3(K3*C_/4/256), dim3(256), 0, stream>>>(w_qkv, Wqkvb, K3*C_/4);
  k_cvt<<<dim3(C_*C_/4/256), dim3(256), 0, stream>>>(w_proj, Wprojb, C_*C_/4);
  // biases
  k_pos_bias   <<<dim3((H_*A_*N_ + 255)/256), dim3(256), 0, stream>>>(an_bias, ah_bias, aw_bias, ac_bias, PBb);
  k_agent_bias_t<<<dim3((H_*A_*N_ + 255)/256), dim3(256), 0, stream>>>(na_bias, ha_bias, wa_bias, ca_bias, ABb);
  // qkv GEMM: (100864 x 384) @ (1152 x 384)^T -> scatter Q/K/V
  k_mm<0><<<dim3((M_TOT/128)*9), dim3(256), 0, stream>>>(Xbf, Wqkvb, C_, 9, Qb, Kb, Vb, nullptr);
  // fused attention middle
  k_attn_fused<<<dim3(B_*H_), dim3(256), 0, stream>>>(Qb, Kb, Vb, PBb, ABb, w_dwc, b_dwc, rep, OPbf);
  // proj GEMM: (100864 x 384) @ (384 x 384)^T + bias -> out
  k_mm<1><<<dim3((M_TOT/128)*3), dim3(256), 0, stream>>>(OPbf, Wprojb, C_, 3, outp, nullptr, nullptr, b_proj);
}